// Round 5
// baseline (196.581 us; speedup 1.0000x reference)
//
#include <hip/hip_runtime.h>

#define N 256
#define C 128
#define H 4
#define D 32
#define NP (N*N)            // 65536 pairs
#define LN_EPS 1e-5f
#define LOG2E 1.4426950408889634f

// Raw workgroup barrier: LDS ordering only -- does NOT drain vmcnt, so
// in-flight global stores keep flying across it. sched_barrier(0) pins
// ordering so the compiler cannot hoist LDS consumers above the waitcnt.
__device__ __forceinline__ void barrier_lgkm() {
    __asm__ volatile("s_waitcnt lgkmcnt(0)" ::: "memory");
    __builtin_amdgcn_sched_barrier(0);
    __builtin_amdgcn_s_barrier();
    __builtin_amdgcn_sched_barrier(0);
}

using f32x4 = __attribute__((ext_vector_type(4))) float;
using bf8   = __attribute__((ext_vector_type(8))) short;   // 8 x bf16 (4 VGPRs)
using u16x4 = __attribute__((ext_vector_type(4))) unsigned short;

__device__ __forceinline__ float bf2f(ushort u) {
    union { uint u; float f; } v; v.u = ((uint)u) << 16; return v.f;
}
__device__ __forceinline__ ushort f2bf(float f) {           // RNE
    union { float f; uint u; } v; v.f = f;
    uint u = v.u;
    u += 0x7fffu + ((u >> 16) & 1u);
    return (ushort)(u >> 16);
}
__device__ __forceinline__ ushort f2bf_trunc(float f) {     // truncate (1 VALU op)
    union { float f; uint u; } v; v.f = f;
    return (ushort)(v.u >> 16);
}

// ---------------------------------------------------------------- weights
__global__ __launch_bounds__(256) void prep_weights(
    const float* __restrict__ wq, const float* __restrict__ wk,
    const float* __restrict__ wv, const float* __restrict__ wg,
    const float* __restrict__ wb, const float* __restrict__ wo,
    ushort* __restrict__ Wcat, ushort* __restrict__ WbPad, ushort* __restrict__ Wo)
{
    int t = blockIdx.x * 256 + threadIdx.x;    // 65536 threads
    const float scale = 0.17677669529663689f * LOG2E;
    float v;
    if (t < 16384)       v = wq[t] * scale;
    else if (t < 32768)  v = wk[t - 16384];
    else if (t < 49152)  v = wv[t - 32768];
    else                 v = wg[t - 49152];
    Wcat[t] = f2bf(v);
    if (t < 16384) Wo[t] = f2bf(wo[t]);
    if (t < 2048)  WbPad[t] = (t < 512) ? f2bf(wb[t]) : (ushort)0;
}

// ---------------------------------------------------------------- fused LN + tri + QKVG
// Grid (nt=4, mt=1024): each block does LN for one 64-pair tile (recomputed
// per nt -- x re-reads are L3-served since nt is the fast grid dim) plus ONE
// of the four projections. 4096 blocks / 16 per CU break the round-4 convoy:
// blocks at different phases (LN / MFMA / epilogue) hide each other's
// latency. Per-block serial chain is ~4 phases instead of ~12.
__global__ __launch_bounds__(512, 4) void ln_proj(
    const float* __restrict__ x, const float* __restrict__ lnw,
    const float* __restrict__ lnb, const ushort* __restrict__ Wcat,
    const ushort* __restrict__ WbPad, const float* __restrict__ bg,
    ushort* __restrict__ qb, ushort* __restrict__ kb,
    ushort* __restrict__ vbT, ushort* __restrict__ gate,
    ushort* __restrict__ tri_p)
{
    __shared__ ushort At[64 * 128];    // 16 KB: LN tile, then epilogue staging
    int nt = blockIdx.x;               // 0..3   (q,k,v,gate)
    int mt = blockIdx.y;               // 0..1023
    int t  = threadIdx.x;
    int wave = t >> 6, lane = t & 63;
    int lane32 = lane & 31, rsel = lane >> 5;

    // ---- Stage A: LayerNorm 64 rows of x -> At (bf16, 16B-chunk XOR swizzle)
    {
        const float4 w4 = ((const float4*)lnw)[lane32];
        const float4 b4 = ((const float4*)lnb)[lane32];
        const float* xb = x + (size_t)mt * 64 * C;
        float4 xv[4];
        #pragma unroll
        for (int pp = 0; pp < 4; pp++) {
            int r = pp * 16 + wave * 2 + rsel;
            xv[pp] = ((const float4*)(xb + r * C))[lane32];
        }
        #pragma unroll
        for (int pp = 0; pp < 4; pp++) {
            int r = pp * 16 + wave * 2 + rsel;
            float4 v = xv[pp];
            float s  = v.x + v.y + v.z + v.w;
            float ss = v.x*v.x + v.y*v.y + v.z*v.z + v.w*v.w;
            #pragma unroll
            for (int m = 1; m < 32; m <<= 1) {
                s  += __shfl_xor(s, m, 64);
                ss += __shfl_xor(ss, m, 64);
            }
            float mean = s * (1.f / 128.f);
            float var  = ss * (1.f / 128.f) - mean * mean;
            float rstd = rsqrtf(var + LN_EPS);
            u16x4 o;
            o[0] = f2bf((v.x - mean) * rstd * w4.x + b4.x);
            o[1] = f2bf((v.y - mean) * rstd * w4.y + b4.y);
            o[2] = f2bf((v.z - mean) * rstd * w4.z + b4.z);
            o[3] = f2bf((v.w - mean) * rstd * w4.w + b4.w);
            int c8 = lane32 >> 1;
            int chunk = r * 16 + (c8 ^ (r & 7));
            *(u16x4*)&At[chunk * 8 + (lane32 & 1) * 4] = o;
        }
    }
    barrier_lgkm();

    int lrow = lane & 15, quad = lane >> 4;
    int wr = wave >> 2, wc = wave & 3;      // wr: 32-row strip, wc: 32-col strip

    // A fragments: hoist to registers once.
    bf8 afr[4][2];
    #pragma unroll
    for (int ks = 0; ks < 4; ks++) {
        int c8 = ks * 4 + quad;
        #pragma unroll
        for (int mi = 0; mi < 2; mi++) {
            int row = wr * 32 + mi * 16 + lrow;
            afr[ks][mi] = *(const bf8*)&At[(row * 16 + (c8 ^ (row & 7))) * 8];
        }
    }

    // ---- triangle bias (nt==0 blocks, wc==0 waves): At @ WbPad^T -> tri_p.
    if (nt == 0 && wc == 0) {
        f32x4 at0 = (f32x4){0.f,0.f,0.f,0.f}, at1 = (f32x4){0.f,0.f,0.f,0.f};
        #pragma unroll
        for (int ks = 0; ks < 4; ks++) {
            bf8 bt = *(const bf8*)(WbPad + lrow * C + (ks * 4 + quad) * 8);
            at0 = __builtin_amdgcn_mfma_f32_16x16x32_bf16(afr[ks][0], bt, at0, 0, 0, 0);
            at1 = __builtin_amdgcn_mfma_f32_16x16x32_bf16(afr[ks][1], bt, at1, 0, 0, 0);
        }
        if (lrow < 4) {                     // lrow = h
            int q = mt >> 2;
            int qc = q >> 4, quadq = (q >> 2) & 3, rr = q & 3;
            #pragma unroll
            for (int mi = 0; mi < 2; mi++) {
                #pragma unroll
                for (int r = 0; r < 4; r++) {
                    int k = (mt & 3) * 64 + wr * 32 + mi * 16 + quad * 4 + r;
                    int n = k >> 4, lk = k & 15;
                    int lanet = quadq * 16 + lk;
                    int v2 = n * 4 + rr, j = v2 >> 3, m2 = v2 & 7;
                    float val = (mi == 0) ? at0[r] : at1[r];
                    tri_p[lrow * 65536 + ((qc * 8 + j) * 64 + lanet) * 8 + m2] =
                        f2bf(val * LOG2E);
                }
            }
        }
    }

    // ---- this block's N-tile: B-frags direct from L2-resident Wcat.
    const ushort* Wt = Wcat + (size_t)nt * 128 * C;
    f32x4 acc[2][2];
    #pragma unroll
    for (int mi = 0; mi < 2; mi++)
        #pragma unroll
        for (int ni = 0; ni < 2; ni++) acc[mi][ni] = (f32x4){0.f, 0.f, 0.f, 0.f};

    #pragma unroll
    for (int ks = 0; ks < 4; ks++) {
        int c8 = ks * 4 + quad;
        bf8 b0 = *(const bf8*)(Wt + (size_t)(wc * 32 + lrow)      * C + c8 * 8);
        bf8 b1 = *(const bf8*)(Wt + (size_t)(wc * 32 + 16 + lrow) * C + c8 * 8);
        acc[0][0] = __builtin_amdgcn_mfma_f32_16x16x32_bf16(afr[ks][0], b0, acc[0][0], 0, 0, 0);
        acc[0][1] = __builtin_amdgcn_mfma_f32_16x16x32_bf16(afr[ks][0], b1, acc[0][1], 0, 0, 0);
        acc[1][0] = __builtin_amdgcn_mfma_f32_16x16x32_bf16(afr[ks][1], b0, acc[1][0], 0, 0, 0);
        acc[1][1] = __builtin_amdgcn_mfma_f32_16x16x32_bf16(afr[ks][1], b1, acc[1][1], 0, 0, 0);
    }

    barrier_lgkm();                    // A-frag readers done -> safe to restage
    if (nt == 2) {
        // transposed staging (col-major), then 128B-contiguous vbT stores
        #pragma unroll
        for (int mi = 0; mi < 2; mi++) {
            #pragma unroll
            for (int ni = 0; ni < 2; ni++) {
                int col = wc * 32 + ni * 16 + lrow;            // h*D+d
                #pragma unroll
                for (int r = 0; r < 4; r++) {
                    int keyl = wr * 32 + mi * 16 + quad * 4 + r;   // 0..63
                    At[col * 64 + (keyl ^ ((col & 7) << 3))] = f2bf(acc[mi][ni][r]);
                }
            }
        }
        barrier_lgkm();
        int i_row = mt >> 2, kq = mt & 3;
        #pragma unroll
        for (int itr = 0; itr < 2; itr++) {
            int oidx = itr * 512 + t;          // 0..1023
            int col = oidx >> 3, kc = oidx & 7;
            bf8 val = *(const bf8*)&At[col * 64 + ((kc * 8) ^ ((col & 7) << 3))];
            *(bf8*)&vbT[(size_t)(i_row * 128 + col) * N + kq * 64 + kc * 8] = val;
        }
    } else {
        ushort* dst = (nt == 0) ? qb : (nt == 1) ? kb : gate;
        float g0 = 0.f, g1 = 0.f;
        if (nt == 3) { g0 = bg[wc * 32 + lrow]; g1 = bg[wc * 32 + 16 + lrow]; }
        #pragma unroll
        for (int mi = 0; mi < 2; mi++) {
            #pragma unroll
            for (int ni = 0; ni < 2; ni++) {
                int col = wc * 32 + ni * 16 + lrow;
                #pragma unroll
                for (int r = 0; r < 4; r++) {
                    int row = wr * 32 + mi * 16 + quad * 4 + r;
                    float vv = acc[mi][ni][r];
                    if (nt == 3)
                        vv = 1.f / (1.f + __expf(-(vv + ((ni == 0) ? g0 : g1))));
                    At[(row * 16 + ((col >> 3) ^ (row & 7))) * 8 + (col & 7)] = f2bf(vv);
                }
            }
        }
        barrier_lgkm();
        #pragma unroll
        for (int itr = 0; itr < 2; itr++) {
            int oidx = itr * 512 + t;          // 0..1023
            int row = oidx >> 4, c8 = oidx & 15;
            bf8 val = *(const bf8*)&At[(row * 16 + (c8 ^ (row & 7))) * 8];
            *(bf8*)&dst[(size_t)(mt * 64 + row) * C + c8 * 8] = val;
        }
    }
}

// ---------------------------------------------------------------- attention
// grid (i=256, h=4), 512 threads = 8 waves, 2 q-chunks (16 rows) per wave.
// K/V staged coalesced into LDS in exact MFMA fragment order. aq fragments
// prefetched at entry; setprio(1) around MFMA clusters.
__global__ __launch_bounds__(512, 4) void attn_kernel(
    const ushort* __restrict__ qb, const ushort* __restrict__ kb,
    const ushort* __restrict__ vbT, const ushort* __restrict__ tri_p,
    const float* __restrict__ mask, ushort* __restrict__ ob)
{
    __shared__ ushort Kf[8192];       // 16 KB: chunk c = kn*64+lane, 8 ushorts each
    __shared__ ushort Vf[8192];       // 16 KB: chunk c = nv*512+ks*64+lane, XOR-swizzled
    __shared__ ushort Pf[8][2048];    // 32 KB: per-wave 128-key half, A-frag order

    int i  = blockIdx.x;
    int h  = blockIdx.y;
    int t  = threadIdx.x;
    int wave = t >> 6, lane = t & 63;
    int lrow = lane & 15, quad = lane >> 4;

    // ---- prefetch both q-chunk A-fragments (in flight across staging)
    bf8 aqr[2];
    #pragma unroll
    for (int cc = 0; cc < 2; cc++)
        aqr[cc] = *(const bf8*)(qb + (size_t)(i * N + (wave * 2 + cc) * 16 + lrow) * C
                                + h * D + quad * 8);

    // ---- stage K: global row-major (key, d) -> frag order, coalesced
    {
        const ushort* kt = kb + (size_t)(i * N) * C + h * D;
        #pragma unroll
        for (int it = 0; it < 2; it++) {
            int idx = it * 512 + t;                  // 0..1023
            int key = idx >> 2, d0 = (idx & 3) * 8;
            bf8 kv = *(const bf8*)(kt + (size_t)key * C + d0);
            int c = (idx >> 6) * 64 + (idx & 3) * 16 + ((idx >> 2) & 15);
            *(bf8*)&Kf[c * 8] = kv;
        }
    }
    // ---- stage V: vbT tile is contiguous 16 KB, coalesced; swizzled chunks
    {
        const ushort* vt = vbT + (size_t)((i * H + h) * D) * N;
        #pragma unroll
        for (int it = 0; it < 2; it++) {
            int idx = it * 512 + t;                  // 0..1023
            bf8 vv = *(const bf8*)(vt + idx * 8);
            int c = (idx >> 9) * 512 + ((idx >> 2) & 7) * 64 + (idx & 3) * 16 + ((idx >> 5) & 15);
            c ^= (c >> 6) & 7;
            *(bf8*)&Vf[c * 8] = vv;
        }
    }
    // mask bias per lane's 16 key-columns (log2e-folded)
    float mb[16];
    #pragma unroll
    for (int n = 0; n < 16; n++)
        mb[n] = (1e9f * LOG2E) * (mask[i * N + n * 16 + lrow] - 1.0f);
    barrier_lgkm();

    ushort* Pw = &Pf[wave][0];
    const ushort* trih = tri_p + (size_t)h * 65536;
    int pq = quad * 32 + (lrow & 7);       // P-write lane-invariant part
    int l3 = (lrow >> 3) & 1;

    #pragma unroll 1
    for (int cc = 0; cc < 2; cc++) {
        int qc = wave * 2 + cc;            // 0..15
        bf8 aq = cc ? aqr[1] : aqr[0];
        float sum[4] = {0.f, 0.f, 0.f, 0.f};
        f32x4 o[2];
        o[0] = (f32x4){0.f, 0.f, 0.f, 0.f};
        o[1] = (f32x4){0.f, 0.f, 0.f, 0.f};

        #pragma unroll
        for (int half = 0; half < 2; half++) {
            // ---- S = Q K^T for 128 keys (8 MFMAs, K frags conflict-free from LDS)
            f32x4 s8[8];
            __builtin_amdgcn_s_setprio(1);
            #pragma unroll
            for (int n8 = 0; n8 < 8; n8++) {
                bf8 kf = *(const bf8*)&Kf[((half * 8 + n8) * 64 + lane) * 8];
                s8[n8] = __builtin_amdgcn_mfma_f32_16x16x32_bf16(
                    aq, kf, (f32x4){0.f, 0.f, 0.f, 0.f}, 0, 0, 0);
            }
            __builtin_amdgcn_s_setprio(0);
            // tri bias fragments: 4 x 16B coalesced loads (pre-permuted layout)
            const ushort* tp = trih + ((size_t)(qc * 8 + half * 4) * 64 + lane) * 8;
            bf8 tf[4];
            #pragma unroll
            for (int jj = 0; jj < 4; jj++)
                tf[jj] = *(const bf8*)(tp + jj * 512);

            // ---- exp2 softmax (no max-sub; logits tiny) + P write (A-frag order)
            #pragma unroll
            for (int n8 = 0; n8 < 8; n8++) {
                int pa = (n8 >> 1) * 512 + (((n8 << 1) + l3) & 3) * 128 + pq;
                #pragma unroll
                for (int r = 0; r < 4; r++) {
                    float tb = bf2f(((const ushort*)&tf[n8 >> 1])[((n8 & 1) << 2) + r]);
                    float e  = exp2f(s8[n8][r] + tb + mb[half * 8 + n8]);
                    sum[r]  += e;
                    Pw[pa + r * 8] = f2bf_trunc(e);
                }
            }
            // drain wave-private P writes (also guarantees prior P reads done)
            __asm__ volatile("s_waitcnt lgkmcnt(0)" ::: "memory");
            __builtin_amdgcn_sched_barrier(0);

            // ---- O += P V_half (K-dim 128 = 4 ks steps)
            __builtin_amdgcn_s_setprio(1);
            #pragma unroll
            for (int ks = 0; ks < 4; ks++) {
                bf8 ap = *(const bf8*)&Pw[(ks * 64 + lane) * 8];
                int ksg = half * 4 + ks;
                #pragma unroll
                for (int nv = 0; nv < 2; nv++) {
                    int c = nv * 512 + ksg * 64 + (lane ^ (ksg & 7));
                    bf8 bv = *(const bf8*)&Vf[c * 8];
                    o[nv] = __builtin_amdgcn_mfma_f32_16x16x32_bf16(ap, bv, o[nv], 0, 0, 0);
                }
            }
            __builtin_amdgcn_s_setprio(0);
        }
        // row sums -> 1/sum, normalize at epilogue
        #pragma unroll
        for (int r = 0; r < 4; r++) {
            float s = sum[r];
            s += __shfl_xor(s, 1, 64);
            s += __shfl_xor(s, 2, 64);
            s += __shfl_xor(s, 4, 64);
            s += __shfl_xor(s, 8, 64);
            sum[r] = 1.f / s;
        }
        #pragma unroll
        for (int nv = 0; nv < 2; nv++) {
            int d = nv * 16 + lrow;
            #pragma unroll
            for (int r = 0; r < 4; r++) {
                int qg = qc * 16 + quad * 4 + r;
                ob[(size_t)(i * N + qg) * C + h * D + d] = f2bf(o[nv][r] * sum[r]);
            }
        }
    }
}

// ---------------------------------------------------------------- gating + output proj
__global__ __launch_bounds__(512, 4) void out_gemm(
    const ushort* __restrict__ ob, const ushort* __restrict__ gate,
    const ushort* __restrict__ Wo, const float* __restrict__ bo,
    float* __restrict__ out)
{
    __shared__ ushort At[128 * 128];   // 32 KB, swizzled (gated O)
    __shared__ ushort Bt[128 * 128];   // 32 KB, swizzled (Wo)
    int mt = blockIdx.x;               // 0..511
    int t  = threadIdx.x;

    const uint4* Og = (const uint4*)(ob   + (size_t)mt * 128 * C);
    const uint4* Gg = (const uint4*)(gate + (size_t)mt * 128 * C);
    const uint4* Bg = (const uint4*)Wo;
    #pragma unroll
    for (int ii = 0; ii < 4; ii++) {
        int idx = t + ii * 512;                  // 0..2047 chunks
        int row = idx >> 4, c8 = idx & 15;
        int sc = row * 16 + (c8 ^ (row & 7));
        uint4 o4 = Og[idx], g4 = Gg[idx], r4;
        const ushort* os = (const ushort*)&o4;
        const ushort* gs = (const ushort*)&g4;
        ushort* rs = (ushort*)&r4;
        #pragma unroll
        for (int j = 0; j < 8; j++) rs[j] = f2bf(bf2f(os[j]) * bf2f(gs[j]));
        ((uint4*)At)[sc] = r4;
        ((uint4*)Bt)[sc] = Bg[idx];
    }
    barrier_lgkm();

    int wave = t >> 6, lane = t & 63;
    int lrow = lane & 15, quad = lane >> 4;
    int wr = wave >> 1, wc = wave & 1;

    f32x4 acc[2][4];
    #pragma unroll
    for (int mi = 0; mi < 2; mi++)
        #pragma unroll
        for (int ni = 0; ni < 4; ni++) acc[mi][ni] = (f32x4){0.f, 0.f, 0.f, 0.f};

    #pragma unroll
    for (int ks = 0; ks < 4; ks++) {
        int c8 = ks * 4 + quad;
        bf8 a[2], b[4];
        #pragma unroll
        for (int mi = 0; mi < 2; mi++) {
            int row = wr * 32 + mi * 16 + lrow;
            a[mi] = *(const bf8*)&At[(row * 16 + (c8 ^ (row & 7))) * 8];
        }
        #pragma unroll
        for (int ni = 0; ni < 4; ni++) {
            int row = wc * 64 + ni * 16 + lrow;
            b[ni] = *(const bf8*)&Bt[(row * 16 + (c8 ^ (row & 7))) * 8];
        }
        #pragma unroll
        for (int mi = 0; mi < 2; mi++)
            #pragma unroll
            for (int ni = 0; ni < 4; ni++)
                acc[mi][ni] = __builtin_amdgcn_mfma_f32_16x16x32_bf16(a[mi], b[ni], acc[mi][ni], 0, 0, 0);
    }

    #pragma unroll
    for (int mi = 0; mi < 2; mi++) {
        #pragma unroll
        for (int ni = 0; ni < 4; ni++) {
            int col = wc * 64 + ni * 16 + lrow;   // 0..127
            float bias = bo[col];
            #pragma unroll
            for (int r = 0; r < 4; r++) {
                int row = mt * 128 + wr * 32 + mi * 16 + quad * 4 + r;
                out[(size_t)row * C + col] = acc[mi][ni][r] + bias;
            }
        }
    }
}

// ---------------------------------------------------------------- launch
extern "C" void kernel_launch(void* const* d_in, const int* in_sizes, int n_in,
                              void* d_out, int out_size, void* d_ws, size_t ws_size,
                              hipStream_t stream)
{
    const float* x    = (const float*)d_in[0];
    const float* mask = (const float*)d_in[1];
    const float* lnw  = (const float*)d_in[2];
    const float* lnb  = (const float*)d_in[3];
    const float* wb   = (const float*)d_in[4];
    const float* wq   = (const float*)d_in[5];
    const float* wk   = (const float*)d_in[6];
    const float* wv   = (const float*)d_in[7];
    const float* wg   = (const float*)d_in[8];
    const float* bg   = (const float*)d_in[9];
    const float* wo   = (const float*)d_in[10];
    const float* bo   = (const float*)d_in[11];
    float* out = (float*)d_out;

    uintptr_t w = (uintptr_t)d_ws;
    ushort* qb    = (ushort*)w; w += (size_t)NP * C * 2;   // 16 MB
    ushort* kb    = (ushort*)w; w += (size_t)NP * C * 2;   // 16 MB
    ushort* vbT   = (ushort*)w; w += (size_t)NP * C * 2;   // 16 MB (transposed V)
    ushort* gate  = (ushort*)w; w += (size_t)NP * C * 2;   // 16 MB
    ushort* ob    = (ushort*)w; w += (size_t)NP * C * 2;   // 16 MB
    ushort* tri_p = (ushort*)w; w += (size_t)H * NP * 2;   // 0.5 MB
    ushort* Wcat  = (ushort*)w; w += 512 * 128 * 2;
    ushort* WbPad = (ushort*)w; w += 16 * 128 * 2;
    ushort* Wo    = (ushort*)w; w += 128 * 128 * 2;

    prep_weights<<<256, 256, 0, stream>>>(wq, wk, wv, wg, wb, wo, Wcat, WbPad, Wo);
    ln_proj<<<dim3(4, NP / 64), 512, 0, stream>>>(x, lnw, lnb, Wcat, WbPad, bg,
                                                  qb, kb, vbT, gate, tri_p);
    attn_kernel<<<dim3(N, H), 512, 0, stream>>>(qb, kb, vbT, tri_p, mask, ob);
    out_gemm<<<NP / 128, 512, 0, stream>>>(ob, gate, Wo, bo, out);
}

// Round 6
// 184.398 us; speedup vs baseline: 1.0661x; 1.0661x over previous
//
#include <hip/hip_runtime.h>

#define N 256
#define C 128
#define H 4
#define D 32
#define NP (N*N)            // 65536 pairs
#define LN_EPS 1e-5f
#define LOG2E 1.4426950408889634f

// Raw workgroup barrier: LDS ordering only -- does NOT drain vmcnt.
__device__ __forceinline__ void barrier_lgkm() {
    __asm__ volatile("s_waitcnt lgkmcnt(0)" ::: "memory");
    __builtin_amdgcn_sched_barrier(0);
    __builtin_amdgcn_s_barrier();
    __builtin_amdgcn_sched_barrier(0);
}

using f32x4 = __attribute__((ext_vector_type(4))) float;
using bf8   = __attribute__((ext_vector_type(8))) short;   // 8 x bf16 (4 VGPRs)
using u16x4 = __attribute__((ext_vector_type(4))) unsigned short;

__device__ __forceinline__ float bf2f(ushort u) {
    union { uint u; float f; } v; v.u = ((uint)u) << 16; return v.f;
}
__device__ __forceinline__ ushort f2bf(float f) {           // RNE
    union { float f; uint u; } v; v.f = f;
    uint u = v.u;
    u += 0x7fffu + ((u >> 16) & 1u);
    return (ushort)(u >> 16);
}
__device__ __forceinline__ ushort f2bf_trunc(float f) {     // truncate (1 VALU op)
    union { float f; uint u; } v; v.f = f;
    return (ushort)(v.u >> 16);
}

// ---------------------------------------------------------------- weights
__global__ __launch_bounds__(256) void prep_weights(
    const float* __restrict__ wq, const float* __restrict__ wk,
    const float* __restrict__ wv, const float* __restrict__ wg,
    const float* __restrict__ wb, const float* __restrict__ wo,
    ushort* __restrict__ Wcat, ushort* __restrict__ WbPad, ushort* __restrict__ Wo)
{
    int t = blockIdx.x * 256 + threadIdx.x;    // 65536 threads
    const float scale = 0.17677669529663689f * LOG2E;
    float v;
    if (t < 16384)       v = wq[t] * scale;
    else if (t < 32768)  v = wk[t - 16384];
    else if (t < 49152)  v = wv[t - 32768];
    else                 v = wg[t - 49152];
    Wcat[t] = f2bf(v);
    if (t < 16384) Wo[t] = f2bf(wo[t]);
    if (t < 2048)  WbPad[t] = (t < 512) ? f2bf(wb[t]) : (ushort)0;
}

// ---------------------------------------------------------------- fused LN + tri + QKVG
// (R4 form -- best measured variant of this phase, ~52 us.)
__global__ __launch_bounds__(512, 4) void ln_proj(
    const float* __restrict__ x, const float* __restrict__ lnw,
    const float* __restrict__ lnb, const ushort* __restrict__ Wcat,
    const ushort* __restrict__ WbPad, const float* __restrict__ bg,
    ushort* __restrict__ qb, ushort* __restrict__ kb,
    ushort* __restrict__ vbT, ushort* __restrict__ gate,
    ushort* __restrict__ tri_p)
{
    __shared__ ushort At[64 * 128];    // 16 KB: LN tile, then epilogue staging
    int mt = blockIdx.x;               // 0..1023
    int t  = threadIdx.x;
    int wave = t >> 6, lane = t & 63;
    int lane32 = lane & 31, rsel = lane >> 5;

    {
        const float4 w4 = ((const float4*)lnw)[lane32];
        const float4 b4 = ((const float4*)lnb)[lane32];
        const float* xb = x + (size_t)mt * 64 * C;
        float4 xv[4];
        #pragma unroll
        for (int pp = 0; pp < 4; pp++) {
            int r = pp * 16 + wave * 2 + rsel;
            xv[pp] = ((const float4*)(xb + r * C))[lane32];
        }
        #pragma unroll
        for (int pp = 0; pp < 4; pp++) {
            int r = pp * 16 + wave * 2 + rsel;
            float4 v = xv[pp];
            float s  = v.x + v.y + v.z + v.w;
            float ss = v.x*v.x + v.y*v.y + v.z*v.z + v.w*v.w;
            #pragma unroll
            for (int m = 1; m < 32; m <<= 1) {
                s  += __shfl_xor(s, m, 64);
                ss += __shfl_xor(ss, m, 64);
            }
            float mean = s * (1.f / 128.f);
            float var  = ss * (1.f / 128.f) - mean * mean;
            float rstd = rsqrtf(var + LN_EPS);
            u16x4 o;
            o[0] = f2bf((v.x - mean) * rstd * w4.x + b4.x);
            o[1] = f2bf((v.y - mean) * rstd * w4.y + b4.y);
            o[2] = f2bf((v.z - mean) * rstd * w4.z + b4.z);
            o[3] = f2bf((v.w - mean) * rstd * w4.w + b4.w);
            int c8 = lane32 >> 1;
            int chunk = r * 16 + (c8 ^ (r & 7));
            *(u16x4*)&At[chunk * 8 + (lane32 & 1) * 4] = o;
        }
    }
    barrier_lgkm();

    int lrow = lane & 15, quad = lane >> 4;
    int wr = wave >> 2, wc = wave & 3;      // wr: 32-row strip, wc: 32-col strip

    bf8 afr[4][2];
    #pragma unroll
    for (int ks = 0; ks < 4; ks++) {
        int c8 = ks * 4 + quad;
        #pragma unroll
        for (int mi = 0; mi < 2; mi++) {
            int row = wr * 32 + mi * 16 + lrow;
            afr[ks][mi] = *(const bf8*)&At[(row * 16 + (c8 ^ (row & 7))) * 8];
        }
    }

    if (wc == 0) {
        f32x4 at0 = (f32x4){0.f,0.f,0.f,0.f}, at1 = (f32x4){0.f,0.f,0.f,0.f};
        #pragma unroll
        for (int ks = 0; ks < 4; ks++) {
            bf8 bt = *(const bf8*)(WbPad + lrow * C + (ks * 4 + quad) * 8);
            at0 = __builtin_amdgcn_mfma_f32_16x16x32_bf16(afr[ks][0], bt, at0, 0, 0, 0);
            at1 = __builtin_amdgcn_mfma_f32_16x16x32_bf16(afr[ks][1], bt, at1, 0, 0, 0);
        }
        if (lrow < 4) {                     // lrow = h
            int q = mt >> 2;
            int qc = q >> 4, quadq = (q >> 2) & 3, rr = q & 3;
            #pragma unroll
            for (int mi = 0; mi < 2; mi++) {
                #pragma unroll
                for (int r = 0; r < 4; r++) {
                    int k = (mt & 3) * 64 + wr * 32 + mi * 16 + quad * 4 + r;
                    int n = k >> 4, lk = k & 15;
                    int lanet = quadq * 16 + lk;
                    int v2 = n * 4 + rr, j = v2 >> 3, m2 = v2 & 7;
                    float val = (mi == 0) ? at0[r] : at1[r];
                    tri_p[lrow * 65536 + ((qc * 8 + j) * 64 + lanet) * 8 + m2] =
                        f2bf(val * LOG2E);
                }
            }
        }
    }

    #pragma unroll 1
    for (int nt = 0; nt < 4; nt++) {
        const ushort* Wt = Wcat + (size_t)nt * 128 * C;
        f32x4 acc[2][2];
        #pragma unroll
        for (int mi = 0; mi < 2; mi++)
            #pragma unroll
            for (int ni = 0; ni < 2; ni++) acc[mi][ni] = (f32x4){0.f, 0.f, 0.f, 0.f};

        #pragma unroll
        for (int ks = 0; ks < 4; ks++) {
            int c8 = ks * 4 + quad;
            bf8 b0 = *(const bf8*)(Wt + (size_t)(wc * 32 + lrow)      * C + c8 * 8);
            bf8 b1 = *(const bf8*)(Wt + (size_t)(wc * 32 + 16 + lrow) * C + c8 * 8);
            acc[0][0] = __builtin_amdgcn_mfma_f32_16x16x32_bf16(afr[ks][0], b0, acc[0][0], 0, 0, 0);
            acc[0][1] = __builtin_amdgcn_mfma_f32_16x16x32_bf16(afr[ks][0], b1, acc[0][1], 0, 0, 0);
            acc[1][0] = __builtin_amdgcn_mfma_f32_16x16x32_bf16(afr[ks][1], b0, acc[1][0], 0, 0, 0);
            acc[1][1] = __builtin_amdgcn_mfma_f32_16x16x32_bf16(afr[ks][1], b1, acc[1][1], 0, 0, 0);
        }

        barrier_lgkm();
        if (nt == 2) {
            #pragma unroll
            for (int mi = 0; mi < 2; mi++) {
                #pragma unroll
                for (int ni = 0; ni < 2; ni++) {
                    int col = wc * 32 + ni * 16 + lrow;            // h*D+d
                    #pragma unroll
                    for (int r = 0; r < 4; r++) {
                        int keyl = wr * 32 + mi * 16 + quad * 4 + r;   // 0..63
                        At[col * 64 + (keyl ^ ((col & 7) << 3))] = f2bf(acc[mi][ni][r]);
                    }
                }
            }
            barrier_lgkm();
            int i_row = mt >> 2, kq = mt & 3;
            #pragma unroll
            for (int itr = 0; itr < 2; itr++) {
                int oidx = itr * 512 + t;          // 0..1023
                int col = oidx >> 3, kc = oidx & 7;
                bf8 val = *(const bf8*)&At[col * 64 + ((kc * 8) ^ ((col & 7) << 3))];
                *(bf8*)&vbT[(size_t)(i_row * 128 + col) * N + kq * 64 + kc * 8] = val;
            }
        } else {
            ushort* dst = (nt == 0) ? qb : (nt == 1) ? kb : gate;
            float g0 = 0.f, g1 = 0.f;
            if (nt == 3) { g0 = bg[wc * 32 + lrow]; g1 = bg[wc * 32 + 16 + lrow]; }
            #pragma unroll
            for (int mi = 0; mi < 2; mi++) {
                #pragma unroll
                for (int ni = 0; ni < 2; ni++) {
                    int col = wc * 32 + ni * 16 + lrow;
                    #pragma unroll
                    for (int r = 0; r < 4; r++) {
                        int row = wr * 32 + mi * 16 + quad * 4 + r;
                        float vv = acc[mi][ni][r];
                        if (nt == 3)
                            vv = 1.f / (1.f + __expf(-(vv + ((ni == 0) ? g0 : g1))));
                        At[(row * 16 + ((col >> 3) ^ (row & 7))) * 8 + (col & 7)] = f2bf(vv);
                    }
                }
            }
            barrier_lgkm();
            #pragma unroll
            for (int itr = 0; itr < 2; itr++) {
                int oidx = itr * 512 + t;          // 0..1023
                int row = oidx >> 4, c8 = oidx & 15;
                bf8 val = *(const bf8*)&At[(row * 16 + (c8 ^ (row & 7))) * 8];
                *(bf8*)&dst[(size_t)(mt * 64 + row) * C + c8 * 8] = val;
            }
        }
    }
}

// ---------------------------------------------------------------- fused attention + out-proj
// Grid (i=256, qh=2), 512 threads = 8 waves; wave w owns q-chunk qc = qh*8+w
// (16 q-rows). Loops h=0..3: stage K_h/V_h into LDS (frag order), QK^T ->
// exp2 softmax -> PV (per-wave P buffer in A-frag order), then IMMEDIATELY
// projects: (O .* gate) @ Wo[:, h*32:+32]^T accumulated into per-wave f32
// out-acc over all 128 output channels (reusing the P buffer for the
// O->A-frag transpose). Kills the ob round-trip + the out_gemm kernel.
__global__ __launch_bounds__(512, 4) void attn_out(
    const ushort* __restrict__ qb, const ushort* __restrict__ kb,
    const ushort* __restrict__ vbT, const ushort* __restrict__ tri_p,
    const float* __restrict__ mask, const ushort* __restrict__ gate,
    const ushort* __restrict__ Wo, const float* __restrict__ bo,
    float* __restrict__ out)
{
    __shared__ ushort Kf[8192];       // 16 KB, per-head K fragments
    __shared__ ushort Vf[8192];       // 16 KB, per-head V fragments (swizzled)
    __shared__ ushort Pf[8][2048];    // 32 KB: per-wave P / O-transpose buffer

    int i  = blockIdx.x;
    int qh = blockIdx.y;
    int t  = threadIdx.x;
    int wave = t >> 6, lane = t & 63;
    int lrow = lane & 15, quad = lane >> 4;
    int qc = qh * 8 + wave;            // q-chunk 0..15

    // mask bias per lane's 16 key-columns (log2e-folded), head-invariant
    float mb[16];
    #pragma unroll
    for (int n = 0; n < 16; n++)
        mb[n] = (1e9f * LOG2E) * (mask[i * N + n * 16 + lrow] - 1.0f);

    f32x4 oacc[8];
    #pragma unroll
    for (int ct = 0; ct < 8; ct++) oacc[ct] = (f32x4){0.f, 0.f, 0.f, 0.f};

    ushort* Pw = &Pf[wave][0];
    const int pq = quad * 32 + (lrow & 7);
    const int l3 = (lrow >> 3) & 1;

    #pragma unroll 1
    for (int h = 0; h < 4; h++) {
        // issue q-frag load early; consumed after the staging barrier
        bf8 aq = *(const bf8*)(qb + (size_t)(i * N + qc * 16 + lrow) * C
                               + h * D + quad * 8);
        barrier_lgkm();                 // prior head's Kf/Vf readers done
        // ---- stage K_h: row-major (key, d) -> frag order, coalesced
        {
            const ushort* kt = kb + (size_t)(i * N) * C + h * D;
            #pragma unroll
            for (int it = 0; it < 2; it++) {
                int idx = it * 512 + t;                  // 0..1023
                int key = idx >> 2, d0 = (idx & 3) * 8;
                bf8 kv = *(const bf8*)(kt + (size_t)key * C + d0);
                int c = (idx >> 6) * 64 + (idx & 3) * 16 + ((idx >> 2) & 15);
                *(bf8*)&Kf[c * 8] = kv;
            }
        }
        // ---- stage V_h: contiguous 16 KB from vbT, swizzled chunks
        {
            const ushort* vt = vbT + (size_t)((i * H + h) * D) * N;
            #pragma unroll
            for (int it = 0; it < 2; it++) {
                int idx = it * 512 + t;                  // 0..1023
                bf8 vv = *(const bf8*)(vt + idx * 8);
                int c = (idx >> 9) * 512 + ((idx >> 2) & 7) * 64 + (idx & 3) * 16 + ((idx >> 5) & 15);
                c ^= (c >> 6) & 7;
                *(bf8*)&Vf[c * 8] = vv;
            }
        }
        barrier_lgkm();

        float sum[4] = {0.f, 0.f, 0.f, 0.f};
        f32x4 o[2];
        o[0] = (f32x4){0.f, 0.f, 0.f, 0.f};
        o[1] = (f32x4){0.f, 0.f, 0.f, 0.f};
        const ushort* trih = tri_p + (size_t)h * 65536;

        #pragma unroll
        for (int half = 0; half < 2; half++) {
            const ushort* tp = trih + ((size_t)(qc * 8 + half * 4) * 64 + lane) * 8;
            // ---- S = Q K^T in pairs (keeps s-regs small), exp2 + P write
            #pragma unroll
            for (int p = 0; p < 4; p++) {
                bf8 tf = *(const bf8*)(tp + p * 512);
                #pragma unroll
                for (int j = 0; j < 2; j++) {
                    int n8 = p * 2 + j;
                    bf8 kf = *(const bf8*)&Kf[((half * 8 + n8) * 64 + lane) * 8];
                    f32x4 s = __builtin_amdgcn_mfma_f32_16x16x32_bf16(
                        aq, kf, (f32x4){0.f, 0.f, 0.f, 0.f}, 0, 0, 0);
                    int pa = (n8 >> 1) * 512 + (((n8 << 1) + l3) & 3) * 128 + pq;
                    #pragma unroll
                    for (int r = 0; r < 4; r++) {
                        float tb = bf2f(((const ushort*)&tf)[j * 4 + r]);
                        float e  = exp2f(s[r] + tb + mb[half * 8 + n8]);
                        sum[r]  += e;
                        Pw[pa + r * 8] = f2bf_trunc(e);
                    }
                }
            }
            // drain wave-private P writes (also guarantees prior P reads done)
            __asm__ volatile("s_waitcnt lgkmcnt(0)" ::: "memory");
            __builtin_amdgcn_sched_barrier(0);

            // ---- O += P V_half (K-dim 128 = 4 ks steps)
            __builtin_amdgcn_s_setprio(1);
            #pragma unroll
            for (int ks = 0; ks < 4; ks++) {
                bf8 ap = *(const bf8*)&Pw[(ks * 64 + lane) * 8];
                int ksg = half * 4 + ks;
                #pragma unroll
                for (int nv = 0; nv < 2; nv++) {
                    int c = nv * 512 + ksg * 64 + (lane ^ (ksg & 7));
                    bf8 bv = *(const bf8*)&Vf[c * 8];
                    o[nv] = __builtin_amdgcn_mfma_f32_16x16x32_bf16(ap, bv, o[nv], 0, 0, 0);
                }
            }
            __builtin_amdgcn_s_setprio(0);
        }

        // ---- normalize rows, multiply gate, transpose O to A-frag order
        #pragma unroll
        for (int r = 0; r < 4; r++) {
            float s = sum[r];
            s += __shfl_xor(s, 1, 64);
            s += __shfl_xor(s, 2, 64);
            s += __shfl_xor(s, 4, 64);
            s += __shfl_xor(s, 8, 64);
            sum[r] = 1.f / s;
        }
        const ushort* gt = gate + (size_t)(i * N + qc * 16) * C + h * D;
        #pragma unroll
        for (int nv = 0; nv < 2; nv++) {
            #pragma unroll
            for (int r = 0; r < 4; r++) {
                float g = bf2f(gt[(quad * 4 + r) * C + nv * 16 + lrow]);
                float val = o[nv][r] * sum[r] * g;
                Pw[(nv * 2 + l3) * 128 + pq + r * 8] = f2bf(val);
            }
        }
        __asm__ volatile("s_waitcnt lgkmcnt(0)" ::: "memory");
        __builtin_amdgcn_sched_barrier(0);

        // ---- out-proj partial: (O.*g)[16,32] @ Wo[:, h*32:+32]^T -> oacc
        bf8 ap = *(const bf8*)&Pw[lane * 8];
        __builtin_amdgcn_s_setprio(1);
        #pragma unroll
        for (int ct = 0; ct < 8; ct++) {
            bf8 wv = *(const bf8*)(Wo + (size_t)(ct * 16 + lrow) * 128 + h * D + quad * 8);
            oacc[ct] = __builtin_amdgcn_mfma_f32_16x16x32_bf16(ap, wv, oacc[ct], 0, 0, 0);
        }
        __builtin_amdgcn_s_setprio(0);
    }

    // ---- epilogue: + bias, fp32 stores
    #pragma unroll
    for (int ct = 0; ct < 8; ct++) {
        float bias = bo[ct * 16 + lrow];
        #pragma unroll
        for (int r = 0; r < 4; r++) {
            int qg = qc * 16 + quad * 4 + r;
            out[(size_t)(i * N + qg) * C + ct * 16 + lrow] = oacc[ct][r] + bias;
        }
    }
}

// ---------------------------------------------------------------- launch
extern "C" void kernel_launch(void* const* d_in, const int* in_sizes, int n_in,
                              void* d_out, int out_size, void* d_ws, size_t ws_size,
                              hipStream_t stream)
{
    const float* x    = (const float*)d_in[0];
    const float* mask = (const float*)d_in[1];
    const float* lnw  = (const float*)d_in[2];
    const float* lnb  = (const float*)d_in[3];
    const float* wb   = (const float*)d_in[4];
    const float* wq   = (const float*)d_in[5];
    const float* wk   = (const float*)d_in[6];
    const float* wv   = (const float*)d_in[7];
    const float* wg   = (const float*)d_in[8];
    const float* bg   = (const float*)d_in[9];
    const float* wo   = (const float*)d_in[10];
    const float* bo   = (const float*)d_in[11];
    float* out = (float*)d_out;

    uintptr_t w = (uintptr_t)d_ws;
    ushort* qb    = (ushort*)w; w += (size_t)NP * C * 2;   // 16 MB
    ushort* kb    = (ushort*)w; w += (size_t)NP * C * 2;   // 16 MB
    ushort* vbT   = (ushort*)w; w += (size_t)NP * C * 2;   // 16 MB (transposed V)
    ushort* gate  = (ushort*)w; w += (size_t)NP * C * 2;   // 16 MB
    ushort* tri_p = (ushort*)w; w += (size_t)H * NP * 2;   // 0.5 MB
    ushort* Wcat  = (ushort*)w; w += 512 * 128 * 2;
    ushort* WbPad = (ushort*)w; w += 16 * 128 * 2;
    ushort* Wo    = (ushort*)w; w += 128 * 128 * 2;

    prep_weights<<<256, 256, 0, stream>>>(wq, wk, wv, wg, wb, wo, Wcat, WbPad, Wo);
    ln_proj<<<NP / 64, 512, 0, stream>>>(x, lnw, lnb, Wcat, WbPad, bg,
                                         qb, kb, vbT, gate, tri_p);
    attn_out<<<dim3(N, 2), 512, 0, stream>>>(qb, kb, vbT, tri_p, mask, gate,
                                             Wo, bo, out);
}